// Round 1
// baseline (1709.362 us; speedup 1.0000x reference)
//
#include <hip/hip_runtime.h>
#include <hip/hip_bf16.h>

// FP8Linear: emulated-fp8 quantize (scale=1) of x[M,K] and w[N,K], then
// out[M,N] = Xq @ Wq^T + bias, f32.
// Strategy: quantized values have <=4 significant bits -> exact in bf16.
// Pass 1: quantize f32 -> bf16 into d_ws. Pass 2: bf16 MFMA GEMM (m97-style
// 128x128 tile, BK=64, global_load_lds width=16), f32 accum, bias epilogue.

typedef short bf16x8 __attribute__((ext_vector_type(8)));
typedef float f32x4 __attribute__((ext_vector_type(4)));

#define BM 128
#define BN 128
#define BK 64

__device__ __forceinline__ unsigned short quant1(float v) {
    // clip(v,-448,448); e=floor(log2(|v|+1e-10)); m=2^(e-3); q=rint(v/m)*m
    float s = fminf(fmaxf(v, -448.0f), 448.0f);
    float e = floorf(log2f(fabsf(s) + 1e-10f));
    float m = exp2f(e - 3.0f);
    float q = rintf(s / m) * m;
    // q has <=4 significant bits -> low 16 bits of f32 repr are zero:
    // truncation to bf16 is exact.
    return (unsigned short)(__float_as_uint(q) >> 16);
}

__global__ __launch_bounds__(256) void quant_kernel(
    const float4* __restrict__ in, ushort4* __restrict__ out, int n4) {
    int i = blockIdx.x * blockDim.x + threadIdx.x;
    if (i >= n4) return;
    float4 v = in[i];
    ushort4 r;
    r.x = quant1(v.x);
    r.y = quant1(v.y);
    r.z = quant1(v.z);
    r.w = quant1(v.w);
    out[i] = r;
}

__device__ __forceinline__ void gload_lds16(const void* g, void* l) {
    __builtin_amdgcn_global_load_lds(
        (const __attribute__((address_space(1))) void*)g,
        (__attribute__((address_space(3))) void*)l,
        16, 0, 0);
}

// A: Xq [M][K] bf16(as short), B: Wq [N][K] bf16(as short), C: [M][N] f32
__global__ __launch_bounds__(256) void gemm_bias_kernel(
    const short* __restrict__ A, const short* __restrict__ B,
    const float* __restrict__ bias, float* __restrict__ C,
    int M, int N, int K) {
    __shared__ short lA[BM * BK];  // 16 KiB
    __shared__ short lB[BN * BK];  // 16 KiB

    const int bn = blockIdx.x, bm = blockIdx.y;
    const int tid = threadIdx.x;
    const int lane = tid & 63;
    const int wave = tid >> 6;
    const int wr = wave >> 1;  // wave row (2x2 wave grid, each 64x64)
    const int wc = wave & 1;

    const int row0 = bm * BM, col0 = bn * BN;

    f32x4 acc[4][4] = {};

    const int cl = lane & 15;      // fragment lane-col
    const int kg = (lane >> 4) * 8;  // fragment k-group offset

    for (int kt = 0; kt < K; kt += BK) {
        // --- stage A,B tiles: 256 thr x 16B x 4 issues = 16KB each ---
#pragma unroll
        for (int c = 0; c < 4; ++c) {
            int e = c * 2048 + tid * 8;      // element index in tile
            int r = e >> 6, k = e & 63;      // [128][64] row-major
            gload_lds16(A + (size_t)(row0 + r) * K + kt + k, lA + e);
        }
#pragma unroll
        for (int c = 0; c < 4; ++c) {
            int e = c * 2048 + tid * 8;
            int r = e >> 6, k = e & 63;
            gload_lds16(B + (size_t)(col0 + r) * K + kt + k, lB + e);
        }
        __syncthreads();  // compiler emits vmcnt(0) drain before barrier

        // --- compute: 2 k-subtiles of 32, 4x4 fragments of 16x16 ---
#pragma unroll
        for (int kk = 0; kk < BK; kk += 32) {
            bf16x8 af[4], bf[4];
#pragma unroll
            for (int m = 0; m < 4; ++m)
                af[m] = *(const bf16x8*)(lA + (wr * 64 + m * 16 + cl) * BK + kk + kg);
#pragma unroll
            for (int n = 0; n < 4; ++n)
                bf[n] = *(const bf16x8*)(lB + (wc * 64 + n * 16 + cl) * BK + kk + kg);
#pragma unroll
            for (int m = 0; m < 4; ++m)
#pragma unroll
                for (int n = 0; n < 4; ++n)
                    acc[m][n] = __builtin_amdgcn_mfma_f32_16x16x32_bf16(
                        af[m], bf[n], acc[m][n], 0, 0, 0);
        }
        __syncthreads();
    }

    // --- epilogue: C/D layout col=lane&15, row=(lane>>4)*4+j ---
    const int rg = (lane >> 4) * 4;
#pragma unroll
    for (int n = 0; n < 4; ++n) {
        int col = col0 + wc * 64 + n * 16 + cl;
        float bv = bias[col];
#pragma unroll
        for (int m = 0; m < 4; ++m) {
            int rowb = row0 + wr * 64 + m * 16 + rg;
#pragma unroll
            for (int j = 0; j < 4; ++j) {
                C[(size_t)(rowb + j) * N + col] = acc[m][n][j] + bv;
            }
        }
    }
}

extern "C" void kernel_launch(void* const* d_in, const int* in_sizes, int n_in,
                              void* d_out, int out_size, void* d_ws, size_t ws_size,
                              hipStream_t stream) {
    const float* x = (const float*)d_in[0];     // [M,K]
    const float* w = (const float*)d_in[1];     // [N,K]
    const float* bias = (const float*)d_in[2];  // [N]
    float* out = (float*)d_out;

    const int N = in_sizes[2];                 // 16384
    const int K = in_sizes[1] / N;             // 4096
    const int M = in_sizes[0] / K;             // 8192

    short* xq = (short*)d_ws;                  // M*K bf16 = 64 MiB... 67.1 MB
    short* wq = xq + (size_t)M * K;            // N*K bf16 = 134.2 MB

    int nx4 = M * K / 4;
    int nw4 = N * K / 4;
    quant_kernel<<<(nx4 + 255) / 256, 256, 0, stream>>>(
        (const float4*)x, (ushort4*)xq, nx4);
    quant_kernel<<<(nw4 + 255) / 256, 256, 0, stream>>>(
        (const float4*)w, (ushort4*)wq, nw4);

    dim3 grid(N / BN, M / BM);
    gemm_bias_kernel<<<grid, 256, 0, stream>>>(
        (const short*)xq, (const short*)wq, bias, out, M, N, K);
}

// Round 2
// 1278.106 us; speedup vs baseline: 1.3374x; 1.3374x over previous
//
#include <hip/hip_runtime.h>
#include <hip/hip_bf16.h>

// FP8Linear: emulated-fp8 quantize (scale=1) of x[M,K] and w[N,K], then
// out[M,N] = Xq @ Wq^T + bias, f32.
// Quantized values have <=4 significant bits -> exact in bf16.
// Pass 1: quantize f32 -> bf16 into d_ws.
// Pass 2: bf16 MFMA GEMM, 256x256 tile, BK=64, 8 waves, double-buffered
// 128KB LDS, 4 phases/K-tile (setprio MFMA clusters, counted staging),
// XOR-swizzled LDS (both-sides with global_load_lds), XCD block swizzle.

typedef short bf16x8 __attribute__((ext_vector_type(8)));
typedef float f32x4 __attribute__((ext_vector_type(4)));

#define BM 256
#define BN 256
#define BK 64

__device__ __forceinline__ unsigned short quant1(float v) {
    float s = fminf(fmaxf(v, -448.0f), 448.0f);
    float e = floorf(log2f(fabsf(s) + 1e-10f));
    float m = exp2f(e - 3.0f);
    float q = rintf(s / m) * m;
    return (unsigned short)(__float_as_uint(q) >> 16);  // exact: <=4 sig bits
}

__global__ __launch_bounds__(256) void quant_kernel(
    const float4* __restrict__ in, ushort4* __restrict__ out, int n4) {
    int i = blockIdx.x * blockDim.x + threadIdx.x;
    if (i >= n4) return;
    float4 v = in[i];
    ushort4 r;
    r.x = quant1(v.x);
    r.y = quant1(v.y);
    r.z = quant1(v.z);
    r.w = quant1(v.w);
    out[i] = r;
}

__device__ __forceinline__ void gload_lds16(const void* g, void* l) {
    __builtin_amdgcn_global_load_lds(
        (const __attribute__((address_space(1))) void*)g,
        (__attribute__((address_space(3))) void*)l,
        16, 0, 0);
}

// Swizzled fragment read: logical (row, col) -> lds[row*64 + (col ^ sw)],
// sw = (row&7)<<3 (row&7 == lane&7 for all our fragment rows).
__device__ __forceinline__ bf16x8 frag_ld(const short* base, int row, int col, int sw) {
    return *(const bf16x8*)(base + (row << 6) + (col ^ sw));
}

// Stage one 256x64 bf16 tile: linear LDS dest (global_load_lds constraint),
// inverse-swizzled global source (rule: both-sides-or-neither).
__device__ __forceinline__ void stage_tile(const short* __restrict__ G, int gr0,
                                           int kt, int K, short* ldsbase, int tid) {
#pragma unroll
    for (int c = 0; c < 4; ++c) {
        int e = c * 4096 + tid * 8;          // element index in [256][64] tile
        int row = e >> 6;
        int col = (e & 63) ^ ((row & 7) << 3);
        gload_lds16(G + (size_t)(gr0 + row) * K + kt + col, ldsbase + e);
    }
}

__device__ __forceinline__ void load_af(bf16x8 (&af)[2][2], const short* Ab,
                                        int rbase, int kg, int sw) {
#pragma unroll
    for (int mi = 0; mi < 2; ++mi)
#pragma unroll
        for (int kk = 0; kk < 2; ++kk)
            af[mi][kk] = frag_ld(Ab, rbase + mi * 16, kk * 32 + kg, sw);
}

template <int MBASE>
__device__ __forceinline__ void mfma_quad(f32x4 (&acc)[8][4], const bf16x8 (&af)[2][2],
                                          const bf16x8 (&bfr)[4][2]) {
#pragma unroll
    for (int mi = 0; mi < 2; ++mi)
#pragma unroll
        for (int n = 0; n < 4; ++n)
#pragma unroll
            for (int kk = 0; kk < 2; ++kk)
                acc[MBASE + mi][n] = __builtin_amdgcn_mfma_f32_16x16x32_bf16(
                    af[mi][kk], bfr[n][kk], acc[MBASE + mi][n], 0, 0, 0);
}

// A: Xq [M][K], B: Wq [N][K] (bf16 as short), C: [M][N] f32
__global__ __launch_bounds__(512, 2) void gemm8p(
    const short* __restrict__ A, const short* __restrict__ B,
    const float* __restrict__ bias, float* __restrict__ C,
    int M, int N, int K) {
    extern __shared__ short lds[];  // 2 bufs x (A 16384 + B 16384) shorts = 128KB

    const int tid = threadIdx.x;
    const int lane = tid & 63;
    const int wave = tid >> 6;
    const int wr = wave >> 2;   // 0..1 -> 128 rows each
    const int wc = wave & 3;    // 0..3 -> 64 cols each

    // XCD-aware bijective block swizzle (nwg % 8 == 0)
    const int nwg = gridDim.x;
    const int per = nwg >> 3;
    const int bid = blockIdx.x;
    const int wg = (bid & 7) * per + (bid >> 3);
    const int mtiles = M / BM;
    const int bm = wg % mtiles;
    const int bn = wg / mtiles;

    const int arow0 = bm * BM, brow0 = bn * BN;
    const int NT = K / BK;

    const int rl = lane & 15;
    const int kg = (lane >> 4) << 3;
    const int sw = (lane & 7) << 3;

    f32x4 acc[8][4] = {};

    // prologue: stage tile 0 into buf 0
    stage_tile(A, arow0, 0, K, lds, tid);
    stage_tile(B, brow0, 0, K, lds + 16384, tid);
    asm volatile("s_waitcnt vmcnt(0)" ::: "memory");
    __builtin_amdgcn_s_barrier();

    for (int t = 0; t < NT; ++t) {
        const int cur = t & 1;
        const short* Ab = lds + cur * 32768;
        const short* Bb = Ab + 16384;
        short* An = lds + (cur ^ 1) * 32768;
        short* Bn = An + 16384;
        const bool pf = (t + 1 < NT);
        const int ktn = (t + 1) * BK;

        bf16x8 bfr[4][2];
        const int arb = wr * 128 + rl;
        const int brb = wc * 64 + rl;

        // ---- phase 1: stage A(t+1); read all B frags + A m0-1; MFMA m0-1
        {
            if (pf) stage_tile(A, arow0, ktn, K, An, tid);
#pragma unroll
            for (int n = 0; n < 4; ++n)
#pragma unroll
                for (int kk = 0; kk < 2; ++kk)
                    bfr[n][kk] = frag_ld(Bb, brb + n * 16, kk * 32 + kg, sw);
            bf16x8 af[2][2];
            load_af(af, Ab, arb + 0 * 16, kg, sw);
            __builtin_amdgcn_s_barrier();
            asm volatile("s_waitcnt lgkmcnt(0)" ::: "memory");
            __builtin_amdgcn_sched_barrier(0);
            __builtin_amdgcn_s_setprio(1);
            mfma_quad<0>(acc, af, bfr);
            __builtin_amdgcn_s_setprio(0);
            __builtin_amdgcn_s_barrier();
        }
        // ---- phase 2: stage B(t+1); A m2-3
        {
            if (pf) stage_tile(B, brow0, ktn, K, Bn, tid);
            bf16x8 af[2][2];
            load_af(af, Ab, arb + 2 * 16, kg, sw);
            __builtin_amdgcn_s_barrier();
            asm volatile("s_waitcnt lgkmcnt(0)" ::: "memory");
            __builtin_amdgcn_sched_barrier(0);
            __builtin_amdgcn_s_setprio(1);
            mfma_quad<2>(acc, af, bfr);
            __builtin_amdgcn_s_setprio(0);
            __builtin_amdgcn_s_barrier();
        }
        // ---- phase 3: A m4-5
        {
            bf16x8 af[2][2];
            load_af(af, Ab, arb + 4 * 16, kg, sw);
            __builtin_amdgcn_s_barrier();
            asm volatile("s_waitcnt lgkmcnt(0)" ::: "memory");
            __builtin_amdgcn_sched_barrier(0);
            __builtin_amdgcn_s_setprio(1);
            mfma_quad<4>(acc, af, bfr);
            __builtin_amdgcn_s_setprio(0);
            __builtin_amdgcn_s_barrier();
        }
        // ---- phase 4: A m6-7; tile-boundary drain of own staging loads
        {
            bf16x8 af[2][2];
            load_af(af, Ab, arb + 6 * 16, kg, sw);
            __builtin_amdgcn_s_barrier();
            asm volatile("s_waitcnt lgkmcnt(0)" ::: "memory");
            __builtin_amdgcn_sched_barrier(0);
            __builtin_amdgcn_s_setprio(1);
            mfma_quad<6>(acc, af, bfr);
            __builtin_amdgcn_s_setprio(0);
            asm volatile("s_waitcnt vmcnt(0)" ::: "memory");
            __builtin_amdgcn_s_barrier();  // all waves' staging landed
        }
    }

    // epilogue: D row = (lane>>4)*4 + j (A side), col = lane&15 (B side)
    const int rg = (lane >> 4) * 4;
#pragma unroll
    for (int n = 0; n < 4; ++n) {
        int col = brow0 + wc * 64 + n * 16 + rl;
        float bv = bias[col];
#pragma unroll
        for (int m = 0; m < 8; ++m) {
            int rowb = arow0 + wr * 128 + m * 16 + rg;
#pragma unroll
            for (int j = 0; j < 4; ++j)
                C[(size_t)(rowb + j) * N + col] = acc[m][n][j] + bv;
        }
    }
}

extern "C" void kernel_launch(void* const* d_in, const int* in_sizes, int n_in,
                              void* d_out, int out_size, void* d_ws, size_t ws_size,
                              hipStream_t stream) {
    const float* x = (const float*)d_in[0];     // [M,K]
    const float* w = (const float*)d_in[1];     // [N,K]
    const float* bias = (const float*)d_in[2];  // [N]
    float* out = (float*)d_out;

    const int N = in_sizes[2];                 // 16384
    const int K = in_sizes[1] / N;             // 4096
    const int M = in_sizes[0] / K;             // 8192

    short* xq = (short*)d_ws;
    short* wq = xq + (size_t)M * K;

    int nx4 = M * K / 4;
    int nw4 = N * K / 4;
    quant_kernel<<<(nx4 + 255) / 256, 256, 0, stream>>>(
        (const float4*)x, (ushort4*)xq, nx4);
    quant_kernel<<<(nw4 + 255) / 256, 256, 0, stream>>>(
        (const float4*)w, (ushort4*)wq, nw4);

    static int smem_set = 0;  // idempotent attribute set (deterministic)
    hipFuncSetAttribute((const void*)gemm8p,
                        hipFuncAttributeMaxDynamicSharedMemorySize, 131072);

    int nwg = (M / BM) * (N / BN);  // 32*64 = 2048, %8==0
    gemm8p<<<nwg, 512, 131072, stream>>>(
        (const short*)xq, (const short*)wq, bias, out, M, N, K);
    (void)smem_set;
}